// Round 13
// baseline (240.435 us; speedup 1.0000x reference)
//
#include <hip/hip_runtime.h>
#include <hip/hip_bf16.h>

// Autoregressive LSTM decoder via bf16 MFMA, torch gate order (i,f,g,o).
// B=262144, P=16, H=32, S=25.  One wave = 32 batch rows (round-6 base).
//
// Round-13 change (single variable vs round 6): trans count 8 -> 5 per elem.
//  * sigma(i),sigma(f),sigma(o) exact via exp2 (3 exp; -log2e folded into A).
//  * BOTH tanh via CF9 Pade rational (validated end-to-end in round 10):
//    tanh(x) ~ x(945+105t+t^2)/(945+420t+15t^2), t=x^2, clamp 3.75.
//    g rows now carry RAW g (scale 1.0).
//  * Denominator merging: one rcp for cn (sigf*sigi*Dg), one rcp for
//    h (Dc*(1+eo)).  5 trans + ~28 VALU / element (was 8 trans + ~12).
//  * Carried: per-step NT stores, k-permutation lane-local B-pack,
//    combined-weight fusion, A-fragments in VGPRs.

constexpr int P = 16;
constexpr int H = 32;
constexpr int S = 25;

typedef short        bf16x8 __attribute__((ext_vector_type(8)));
typedef float        f32x16 __attribute__((ext_vector_type(16)));
typedef float        f32x4  __attribute__((ext_vector_type(4)));
typedef unsigned int u32x4  __attribute__((ext_vector_type(4)));

union FragU { u32x4 u; bf16x8 b; };

#if __has_builtin(__builtin_amdgcn_exp2f)
#define EX2 __builtin_amdgcn_exp2f
#else
#define EX2 exp2f
#endif

__device__ __forceinline__ unsigned int pkbf(float lo, float hi) {
    unsigned short a = __builtin_bit_cast(unsigned short, __float2bfloat16(lo));
    unsigned short b = __builtin_bit_cast(unsigned short, __float2bfloat16(hi));
    return (unsigned int)a | ((unsigned int)b << 16);
}

// gate-row scale: i,f,o rows -log2(e) (exp2-ready, gives e^{-x});
//                 g rows 1.0 (raw, consumed by rational tanh)
__device__ __forceinline__ float gate_scale(int r) {
    return (r >= 64 && r < 96) ? 1.0f : -1.4426950408889634f;
}

// ---------------- setup: build bf16 A-fragments into ws -------------------
// steady W_aug[160][48]: r<128: Wcomb=Whh+Wih*Wout (k<32), bias at k=32, 0 pad;
//                        128<=r<144: Wout rows, bout at k=32; r>=144: 0.
//                        gate rows (r<128) scaled by gate_scale(r).
// step0  W0_aug[128][64]: k<16: Wih; 16<=k<48: Whh; k=48: b_ih+b_hh; 0 pad.
// fragment slot: logical k = 16c + 8*(v>>1) + 4*hi + 2*(v&1) + b
// word index: steady ((t*3+c)*64 + lane)*4 + v   (t<5,c<3)
//             step0  3840 + ((t*4+c)*64 + lane)*4 + v  (t<4,c<4)
__global__ void setup_frags(const float* __restrict__ Wih, const float* __restrict__ Whh,
                            const float* __restrict__ bih, const float* __restrict__ bhh,
                            const float* __restrict__ Wout, const float* __restrict__ bout,
                            unsigned int* __restrict__ ws)
{
    auto waug = [&](int r, int k) -> float {
        float s = (r < 128) ? gate_scale(r) : 1.0f;
        if (r < 128) {
            if (k < 32) {
                float a = Whh[r * H + k];
                for (int p = 0; p < P; ++p) a += Wih[r * P + p] * Wout[p * H + k];
                return s * a;
            }
            if (k == 32) {
                float a = bih[r] + bhh[r];
                for (int p = 0; p < P; ++p) a += Wih[r * P + p] * bout[p];
                return s * a;
            }
            return 0.0f;
        } else if (r < 144) {
            int p = r - 128;
            if (k < 32)  return Wout[p * H + k];
            if (k == 32) return bout[p];
            return 0.0f;
        }
        return 0.0f;
    };
    auto w0aug = [&](int r, int k) -> float {
        float s = gate_scale(r);
        if (k < 16)  return s * Wih[r * P + k];
        if (k < 48)  return s * Whh[r * H + (k - 16)];
        if (k == 48) return s * (bih[r] + bhh[r]);
        return 0.0f;
    };

    const int tid = threadIdx.x;
    for (int idx = tid; idx < 5 * 3 * 64 * 4; idx += 256) {
        int v = idx & 3, l = (idx >> 2) & 63, tc = idx >> 8;
        int t = tc / 3, c = tc % 3;
        int r = 32 * t + (l & 31);
        int k = 16 * c + 8 * (v >> 1) + 4 * (l >> 5) + 2 * (v & 1);
        ws[idx] = pkbf(waug(r, k), waug(r, k + 1));
    }
    for (int idx = tid; idx < 4 * 4 * 64 * 4; idx += 256) {
        int v = idx & 3, l = (idx >> 2) & 63, tc = idx >> 8;
        int t = tc / 4, c = tc % 4;
        int r = 32 * t + (l & 31);
        int k = 16 * c + 8 * (v >> 1) + 4 * (l >> 5) + 2 * (v & 1);
        ws[3840 + idx] = pkbf(w0aug(r, k), w0aug(r, k + 1));
    }
}

// ------------------------------- main -------------------------------------
__global__ __launch_bounds__(256, 2) void decoder_mfma(
    const float* __restrict__ x0, const float* __restrict__ h0,
    const float* __restrict__ c0, const unsigned int* __restrict__ ws,
    float* __restrict__ out, int batch)
{
    const int lane = threadIdx.x & 63;
    const int wid  = threadIdx.x >> 6;
    const int bcol = lane & 31;
    const int hi   = lane >> 5;
    const int bg   = (blockIdx.x * 4 + wid) * 32 + bcol;  // this lane's batch row
    if (bg >= batch) return;  // batch % 128 == 0: wave-uniform

    // steady A-fragments: 5 tiles (4 gate quarters + proj) x 3 K-chunks
    FragU A[5][3];
    #pragma unroll
    for (int t = 0; t < 5; ++t)
        #pragma unroll
        for (int c = 0; c < 3; ++c)
            A[t][c].u = *reinterpret_cast<const u32x4*>(ws + ((t * 3 + c) * 64 + lane) * 4);

    // bias B-chunk: logical k=32 (steady) / k=48 (step0) at (hi=0, v=0, lo half)
    FragU Bbias;
    Bbias.u.x = (hi == 0) ? 0x3F80u : 0u;  // bf16(1.0)
    Bbias.u.y = 0u; Bbias.u.z = 0u; Bbias.u.w = 0u;

    // cell state in D-layout: cc[r] <-> c[bg][(r&3) + 8*(r>>2) + 4*hi]
    float cc[16];
    #pragma unroll
    for (int q = 0; q < 4; ++q) {
        f32x4 t = *reinterpret_cast<const f32x4*>(c0 + (size_t)bg * H + q * 8 + 4 * hi);
        cc[q * 4 + 0] = t.x; cc[q * 4 + 1] = t.y; cc[q * 4 + 2] = t.z; cc[q * 4 + 3] = t.w;
    }

    const f32x16 vzero = {};
    f32x16 acc[4];
    FragU Bh[2];

    // ---- step-0 gates: K = [x0(16) | h0(32) | 1], W0_aug fragments ----
    {
        FragU B0[4];
        {
            const float* p = x0 + (size_t)bg * P;
            f32x4 a  = *reinterpret_cast<const f32x4*>(p + 4 * hi);
            f32x4 b4 = *reinterpret_cast<const f32x4*>(p + 8 + 4 * hi);
            B0[0].u.x = pkbf(a.x, a.y);  B0[0].u.y = pkbf(a.z, a.w);
            B0[0].u.z = pkbf(b4.x, b4.y); B0[0].u.w = pkbf(b4.z, b4.w);
        }
        #pragma unroll
        for (int ch = 0; ch < 2; ++ch) {
            const float* p = h0 + (size_t)bg * H + 16 * ch;
            f32x4 a  = *reinterpret_cast<const f32x4*>(p + 4 * hi);
            f32x4 b4 = *reinterpret_cast<const f32x4*>(p + 8 + 4 * hi);
            B0[1 + ch].u.x = pkbf(a.x, a.y);  B0[1 + ch].u.y = pkbf(a.z, a.w);
            B0[1 + ch].u.z = pkbf(b4.x, b4.y); B0[1 + ch].u.w = pkbf(b4.z, b4.w);
        }
        B0[3] = Bbias;

        #pragma unroll
        for (int t = 0; t < 4; ++t) acc[t] = vzero;
        #pragma unroll
        for (int c4 = 0; c4 < 4; ++c4) {
            #pragma unroll
            for (int t = 0; t < 4; ++t) {
                FragU a;
                a.u = *reinterpret_cast<const u32x4*>(ws + 3840 + ((t * 4 + c4) * 64 + lane) * 4);
                acc[t] = __builtin_amdgcn_mfma_f32_32x32x16_bf16(a.b, B0[c4].b, acc[t], 0, 0, 0);
            }
        }
    }

    // ---------------- per-step phases (compile-time indexed) --------------
    // CF9 Pade tanh: N(x)=x(945+105t+t^2), D(x)=945+420t+15t^2, t=x^2
    auto EWPACK = [&]() {
        float hh[16];
        #pragma unroll
        for (int r = 0; r < 16; ++r) {
            const float ei = EX2(acc[0][r]);        // e^{-i}
            const float ef = EX2(acc[1][r]);        // e^{-f}
            const float eo = EX2(acc[3][r]);        // e^{-o}
            // rational tanh(g)
            float g = acc[2][r];
            g = fminf(fmaxf(g, -3.75f), 3.75f);
            const float tg = g * g;
            const float Ng = ((tg + 105.0f) * tg + 945.0f) * g;
            const float Dg = __builtin_fmaf(__builtin_fmaf(15.0f, tg, 420.0f), tg, 945.0f);
            // cn = [c*(1+ei)*Dg + Ng*(1+ef)] / ((1+ef)*(1+ei)*Dg)
            const float ai = 1.0f + ei;
            const float af = 1.0f + ef;
            const float caD = cc[r] * ai * Dg;
            const float num = __builtin_fmaf(Ng, af, caD);
            const float rd  = __builtin_amdgcn_rcpf(af * ai * Dg);
            const float cn  = num * rd;
            cc[r] = cn;
            // h = tanh(cn) * sigma(o) = Nc / (Dc * (1+eo))
            float cm = fminf(fmaxf(cn, -3.75f), 3.75f);
            const float tc = cm * cm;
            const float Nc = ((tc + 105.0f) * tc + 945.0f) * cm;
            const float Dc = __builtin_fmaf(__builtin_fmaf(15.0f, tc, 420.0f), tc, 945.0f);
            const float r2 = __builtin_amdgcn_rcpf(Dc * (1.0f + eo));
            hh[r] = Nc * r2;
        }
        Bh[0].u.x = pkbf(hh[0],  hh[1]);  Bh[0].u.y = pkbf(hh[2],  hh[3]);
        Bh[0].u.z = pkbf(hh[4],  hh[5]);  Bh[0].u.w = pkbf(hh[6],  hh[7]);
        Bh[1].u.x = pkbf(hh[8],  hh[9]);  Bh[1].u.y = pkbf(hh[10], hh[11]);
        Bh[1].u.z = pkbf(hh[12], hh[13]); Bh[1].u.w = pkbf(hh[14], hh[15]);
    };
    auto PROJSTORE = [&](int s) {
        f32x16 px;
        px = __builtin_amdgcn_mfma_f32_32x32x16_bf16(A[4][2].b, Bbias.b, vzero, 0, 0, 0);
        px = __builtin_amdgcn_mfma_f32_32x32x16_bf16(A[4][0].b, Bh[0].b, px,    0, 0, 0);
        px = __builtin_amdgcn_mfma_f32_32x32x16_bf16(A[4][1].b, Bh[1].b, px,    0, 0, 0);
        float* op = out + ((size_t)bg * S + s) * P + 4 * hi;
        f32x4 v0 = {px[0], px[1], px[2], px[3]};
        f32x4 v1 = {px[4], px[5], px[6], px[7]};
        __builtin_nontemporal_store(v0, reinterpret_cast<f32x4*>(op));
        __builtin_nontemporal_store(v1, reinterpret_cast<f32x4*>(op + 8));
    };
    auto GATES = [&]() {
        #pragma unroll
        for (int t = 0; t < 4; ++t) {
            f32x16 a;
            a = __builtin_amdgcn_mfma_f32_32x32x16_bf16(A[t][2].b, Bbias.b, vzero, 0, 0, 0);
            a = __builtin_amdgcn_mfma_f32_32x32x16_bf16(A[t][0].b, Bh[0].b, a,    0, 0, 0);
            a = __builtin_amdgcn_mfma_f32_32x32x16_bf16(A[t][1].b, Bh[1].b, a,    0, 0, 0);
            acc[t] = a;
        }
    };

    // ---- steady loop ----
    for (int s = 0; s < S; ++s) {
        EWPACK();
        PROJSTORE(s);
        if (s + 1 < S) GATES();
    }
}

extern "C" void kernel_launch(void* const* d_in, const int* in_sizes, int n_in,
                              void* d_out, int out_size, void* d_ws, size_t ws_size,
                              hipStream_t stream) {
    const float* x0   = (const float*)d_in[0];
    const float* h0   = (const float*)d_in[1];
    const float* c0   = (const float*)d_in[2];
    const float* Wih  = (const float*)d_in[3];
    const float* Whh  = (const float*)d_in[4];
    const float* bih  = (const float*)d_in[5];
    const float* bhh  = (const float*)d_in[6];
    const float* Wout = (const float*)d_in[7];
    const float* bout = (const float*)d_in[8];
    float* out = (float*)d_out;
    unsigned int* ws = (unsigned int*)d_ws;

    const int batch = in_sizes[0] / P;  // 262144

    hipLaunchKernelGGL(setup_frags, dim3(1), dim3(256), 0, stream,
                       Wih, Whh, bih, bhh, Wout, bout, ws);

    dim3 block(256);                    // 4 waves x 32 batch rows = 128 batch/block
    dim3 grid((batch + 127) / 128);     // 2048 blocks
    hipLaunchKernelGGL(decoder_mfma, grid, block, 0, stream,
                       x0, h0, c0, ws, out, batch);
}

// Round 14
// 240.029 us; speedup vs baseline: 1.0017x; 1.0017x over previous
//
#include <hip/hip_runtime.h>
#include <hip/hip_bf16.h>

// Autoregressive LSTM decoder via bf16 MFMA, torch gate order (i,f,g,o).
// B=262144, P=16, H=32, S=25.  One wave = 32 batch rows (round-6 base).
//
// Round-14 change (single variable vs round 11): PLAIN stores instead of NT.
//  * Round 11 (NT + 4-step batching) = 226us at ~2.1 TB/s write.  The
//    harness fill kernel hits 6.9 TB/s on this buffer with plain stores.
//    Hypothesis: the NT (L2-bypass) write queue caps at ~2 TB/s; plain
//    stores drain through L2 at full rate.  4-step 256B runs keep most
//    128B lines fully covered (modest edge RFO expected).
//  * Carried: 4-step reg-buffered store batching, k-permutation lane-local
//    B-pack, exp2 scales folded into A, shared-denominator sigmoid*tanh.

constexpr int P = 16;
constexpr int H = 32;
constexpr int S = 25;

typedef short        bf16x8 __attribute__((ext_vector_type(8)));
typedef float        f32x16 __attribute__((ext_vector_type(16)));
typedef float        f32x4  __attribute__((ext_vector_type(4)));
typedef unsigned int u32x4  __attribute__((ext_vector_type(4)));

union FragU { u32x4 u; bf16x8 b; };

#if __has_builtin(__builtin_amdgcn_exp2f)
#define EX2 __builtin_amdgcn_exp2f
#else
#define EX2 exp2f
#endif

__device__ __forceinline__ unsigned int pkbf(float lo, float hi) {
    unsigned short a = __builtin_bit_cast(unsigned short, __float2bfloat16(lo));
    unsigned short b = __builtin_bit_cast(unsigned short, __float2bfloat16(hi));
    return (unsigned int)a | ((unsigned int)b << 16);
}

// gate-row exp2 scale: rows [0,32)=i, [32,64)=f, [64,96)=g, [96,128)=o
__device__ __forceinline__ float gate_scale(int r) {
    return (r >= 64 && r < 96) ? -2.8853900817779268f   // g rows: -2*log2(e)
                               : -1.4426950408889634f;  // i,f,o rows: -log2(e)
}

// ---------------- setup: build bf16 A-fragments into ws -------------------
// steady W_aug[160][48]: r<128: Wcomb=Whh+Wih*Wout (k<32), bias at k=32, 0 pad;
//                        128<=r<144: Wout rows, bout at k=32; r>=144: 0.
//                        gate rows (r<128) scaled by gate_scale(r).
// step0  W0_aug[128][64]: k<16: Wih; 16<=k<48: Whh; k=48: b_ih+b_hh; 0 pad.
// fragment slot: logical k = 16c + 8*(v>>1) + 4*hi + 2*(v&1) + b
// word index: steady ((t*3+c)*64 + lane)*4 + v   (t<5,c<3)
//             step0  3840 + ((t*4+c)*64 + lane)*4 + v  (t<4,c<4)
__global__ void setup_frags(const float* __restrict__ Wih, const float* __restrict__ Whh,
                            const float* __restrict__ bih, const float* __restrict__ bhh,
                            const float* __restrict__ Wout, const float* __restrict__ bout,
                            unsigned int* __restrict__ ws)
{
    auto waug = [&](int r, int k) -> float {
        float s = (r < 128) ? gate_scale(r) : 1.0f;
        if (r < 128) {
            if (k < 32) {
                float a = Whh[r * H + k];
                for (int p = 0; p < P; ++p) a += Wih[r * P + p] * Wout[p * H + k];
                return s * a;
            }
            if (k == 32) {
                float a = bih[r] + bhh[r];
                for (int p = 0; p < P; ++p) a += Wih[r * P + p] * bout[p];
                return s * a;
            }
            return 0.0f;
        } else if (r < 144) {
            int p = r - 128;
            if (k < 32)  return Wout[p * H + k];
            if (k == 32) return bout[p];
            return 0.0f;
        }
        return 0.0f;
    };
    auto w0aug = [&](int r, int k) -> float {
        float s = gate_scale(r);
        if (k < 16)  return s * Wih[r * P + k];
        if (k < 48)  return s * Whh[r * H + (k - 16)];
        if (k == 48) return s * (bih[r] + bhh[r]);
        return 0.0f;
    };

    const int tid = threadIdx.x;
    for (int idx = tid; idx < 5 * 3 * 64 * 4; idx += 256) {
        int v = idx & 3, l = (idx >> 2) & 63, tc = idx >> 8;
        int t = tc / 3, c = tc % 3;
        int r = 32 * t + (l & 31);
        int k = 16 * c + 8 * (v >> 1) + 4 * (l >> 5) + 2 * (v & 1);
        ws[idx] = pkbf(waug(r, k), waug(r, k + 1));
    }
    for (int idx = tid; idx < 4 * 4 * 64 * 4; idx += 256) {
        int v = idx & 3, l = (idx >> 2) & 63, tc = idx >> 8;
        int t = tc / 4, c = tc % 4;
        int r = 32 * t + (l & 31);
        int k = 16 * c + 8 * (v >> 1) + 4 * (l >> 5) + 2 * (v & 1);
        ws[3840 + idx] = pkbf(w0aug(r, k), w0aug(r, k + 1));
    }
}

// ------------------------------- main -------------------------------------
__global__ __launch_bounds__(256, 2) void decoder_mfma(
    const float* __restrict__ x0, const float* __restrict__ h0,
    const float* __restrict__ c0, const unsigned int* __restrict__ ws,
    float* __restrict__ out, int batch)
{
    const int lane = threadIdx.x & 63;
    const int wid  = threadIdx.x >> 6;
    const int bcol = lane & 31;
    const int hi   = lane >> 5;
    const int bg   = (blockIdx.x * 4 + wid) * 32 + bcol;  // this lane's batch row
    if (bg >= batch) return;  // batch % 128 == 0: wave-uniform

    // steady A-fragments: 5 tiles (4 gate quarters + proj) x 3 K-chunks
    FragU A[5][3];
    #pragma unroll
    for (int t = 0; t < 5; ++t)
        #pragma unroll
        for (int c = 0; c < 3; ++c)
            A[t][c].u = *reinterpret_cast<const u32x4*>(ws + ((t * 3 + c) * 64 + lane) * 4);

    // bias B-chunk: logical k=32 (steady) / k=48 (step0) at (hi=0, v=0, lo half)
    FragU Bbias;
    Bbias.u.x = (hi == 0) ? 0x3F80u : 0u;  // bf16(1.0)
    Bbias.u.y = 0u; Bbias.u.z = 0u; Bbias.u.w = 0u;

    // cell state in D-layout: cc[r] <-> c[bg][(r&3) + 8*(r>>2) + 4*hi]
    float cc[16];
    #pragma unroll
    for (int q = 0; q < 4; ++q) {
        f32x4 t = *reinterpret_cast<const f32x4*>(c0 + (size_t)bg * H + q * 8 + 4 * hi);
        cc[q * 4 + 0] = t.x; cc[q * 4 + 1] = t.y; cc[q * 4 + 2] = t.z; cc[q * 4 + 3] = t.w;
    }

    const f32x16 vzero = {};
    f32x16 acc[4];
    FragU Bh[2];

    // ---- step-0 gates: K = [x0(16) | h0(32) | 1], W0_aug fragments ----
    {
        FragU B0[4];
        {
            const float* p = x0 + (size_t)bg * P;
            f32x4 a  = *reinterpret_cast<const f32x4*>(p + 4 * hi);
            f32x4 b4 = *reinterpret_cast<const f32x4*>(p + 8 + 4 * hi);
            B0[0].u.x = pkbf(a.x, a.y);  B0[0].u.y = pkbf(a.z, a.w);
            B0[0].u.z = pkbf(b4.x, b4.y); B0[0].u.w = pkbf(b4.z, b4.w);
        }
        #pragma unroll
        for (int ch = 0; ch < 2; ++ch) {
            const float* p = h0 + (size_t)bg * H + 16 * ch;
            f32x4 a  = *reinterpret_cast<const f32x4*>(p + 4 * hi);
            f32x4 b4 = *reinterpret_cast<const f32x4*>(p + 8 + 4 * hi);
            B0[1 + ch].u.x = pkbf(a.x, a.y);  B0[1 + ch].u.y = pkbf(a.z, a.w);
            B0[1 + ch].u.z = pkbf(b4.x, b4.y); B0[1 + ch].u.w = pkbf(b4.z, b4.w);
        }
        B0[3] = Bbias;

        #pragma unroll
        for (int t = 0; t < 4; ++t) acc[t] = vzero;
        #pragma unroll
        for (int c4 = 0; c4 < 4; ++c4) {
            #pragma unroll
            for (int t = 0; t < 4; ++t) {
                FragU a;
                a.u = *reinterpret_cast<const u32x4*>(ws + 3840 + ((t * 4 + c4) * 64 + lane) * 4);
                acc[t] = __builtin_amdgcn_mfma_f32_32x32x16_bf16(a.b, B0[c4].b, acc[t], 0, 0, 0);
            }
        }
    }

    // ---------------- per-step phases (compile-time indexed) --------------
    auto EWPACK = [&]() {
        float hh[16];
        #pragma unroll
        for (int r = 0; r < 16; ++r) {
            const float ei = EX2(acc[0][r]);        // e^{-i}
            const float ef = EX2(acc[1][r]);        // e^{-f}
            const float eg = EX2(acc[2][r]);        // e^{-2g}
            const float eo = EX2(acc[3][r]);        // e^{-o}
            const float r1 = __builtin_amdgcn_rcpf((1.0f + ei) * (1.0f + eg));
            const float tg = (1.0f - eg) * r1;      // sig(i)*tanh(g)
            const float rf = __builtin_amdgcn_rcpf(1.0f + ef);
            const float cn = __builtin_fmaf(cc[r], rf, tg);
            cc[r] = cn;
            const float ec = EX2(cn * -2.8853900817779268f);  // e^{-2cn}
            const float r2 = __builtin_amdgcn_rcpf((1.0f + ec) * (1.0f + eo));
            hh[r] = (1.0f - ec) * r2;               // sig(o)*tanh(cn)
        }
        Bh[0].u.x = pkbf(hh[0],  hh[1]);  Bh[0].u.y = pkbf(hh[2],  hh[3]);
        Bh[0].u.z = pkbf(hh[4],  hh[5]);  Bh[0].u.w = pkbf(hh[6],  hh[7]);
        Bh[1].u.x = pkbf(hh[8],  hh[9]);  Bh[1].u.y = pkbf(hh[10], hh[11]);
        Bh[1].u.z = pkbf(hh[12], hh[13]); Bh[1].u.w = pkbf(hh[14], hh[15]);
    };
    auto PROJ = [&](f32x4& v0, f32x4& v1) {
        f32x16 px;
        px = __builtin_amdgcn_mfma_f32_32x32x16_bf16(A[4][2].b, Bbias.b, vzero, 0, 0, 0);
        px = __builtin_amdgcn_mfma_f32_32x32x16_bf16(A[4][0].b, Bh[0].b, px,    0, 0, 0);
        px = __builtin_amdgcn_mfma_f32_32x32x16_bf16(A[4][1].b, Bh[1].b, px,    0, 0, 0);
        v0 = f32x4{px[0], px[1], px[2], px[3]};
        v1 = f32x4{px[4], px[5], px[6], px[7]};
    };
    auto GATES = [&]() {
        #pragma unroll
        for (int t = 0; t < 4; ++t) {
            f32x16 a;
            a = __builtin_amdgcn_mfma_f32_32x32x16_bf16(A[t][2].b, Bbias.b, vzero, 0, 0, 0);
            a = __builtin_amdgcn_mfma_f32_32x32x16_bf16(A[t][0].b, Bh[0].b, a,    0, 0, 0);
            a = __builtin_amdgcn_mfma_f32_32x32x16_bf16(A[t][1].b, Bh[1].b, a,    0, 0, 0);
            acc[t] = a;
        }
    };

    float* const o = out + (size_t)bg * (S * P) + 4 * hi;

    // 4-step projection buffer (dedicated regs, static indexing)
    f32x4 pa0, pb0, pa1, pb1, pa2, pb2, pa3, pb3;

    // ---- steady loop: 6 blocks of 4 steps + tail step 24 ----
    for (int blk = 0; blk < 6; ++blk) {
        EWPACK(); PROJ(pa0, pb0); GATES();
        EWPACK(); PROJ(pa1, pb1); GATES();
        EWPACK(); PROJ(pa2, pb2); GATES();
        EWPACK(); PROJ(pa3, pb3); GATES();
        // flush: per row a contiguous 256B run (4 steps x 64B), PLAIN stores
        float* ob = o + blk * 4 * P;
        *reinterpret_cast<f32x4*>(ob)              = pa0;
        *reinterpret_cast<f32x4*>(ob + 8)          = pb0;
        *reinterpret_cast<f32x4*>(ob + P)          = pa1;
        *reinterpret_cast<f32x4*>(ob + P + 8)      = pb1;
        *reinterpret_cast<f32x4*>(ob + 2 * P)      = pa2;
        *reinterpret_cast<f32x4*>(ob + 2 * P + 8)  = pb2;
        *reinterpret_cast<f32x4*>(ob + 3 * P)      = pa3;
        *reinterpret_cast<f32x4*>(ob + 3 * P + 8)  = pb3;
    }
    // tail: step 24 (no next gates)
    EWPACK();
    PROJ(pa0, pb0);
    *reinterpret_cast<f32x4*>(o + 24 * P)     = pa0;
    *reinterpret_cast<f32x4*>(o + 24 * P + 8) = pb0;
}

extern "C" void kernel_launch(void* const* d_in, const int* in_sizes, int n_in,
                              void* d_out, int out_size, void* d_ws, size_t ws_size,
                              hipStream_t stream) {
    const float* x0   = (const float*)d_in[0];
    const float* h0   = (const float*)d_in[1];
    const float* c0   = (const float*)d_in[2];
    const float* Wih  = (const float*)d_in[3];
    const float* Whh  = (const float*)d_in[4];
    const float* bih  = (const float*)d_in[5];
    const float* bhh  = (const float*)d_in[6];
    const float* Wout = (const float*)d_in[7];
    const float* bout = (const float*)d_in[8];
    float* out = (float*)d_out;
    unsigned int* ws = (unsigned int*)d_ws;

    const int batch = in_sizes[0] / P;  // 262144

    hipLaunchKernelGGL(setup_frags, dim3(1), dim3(256), 0, stream,
                       Wih, Whh, bih, bhh, Wout, bout, ws);

    dim3 block(256);                    // 4 waves x 32 batch rows = 128 batch/block
    dim3 grid((batch + 127) / 128);     // 2048 blocks
    hipLaunchKernelGGL(decoder_mfma, grid, block, 0, stream,
                       x0, h0, c0, ws, out, batch);
}